// Round 8
// baseline (383.691 us; speedup 1.0000x reference)
//
#include <hip/hip_runtime.h>

typedef short short8 __attribute__((ext_vector_type(8)));
typedef __bf16 bf16x8 __attribute__((ext_vector_type(8)));
typedef float f32x4 __attribute__((ext_vector_type(4)));

namespace {

constexpr int kNodeW = 320;   // NS + 3*NV
constexpr int kOutW  = 320;   // NS + 3*VOUT

// wsv frag indices (packed by pack_weights); 1 frag = 64 lanes * 16 B = 1 KB
constexpr int F_W1 = 0;    // kb*4 + nt (kb<2)
constexpr int F_W2 = 8;
constexpr int F_W3 = 16;   // kb*28 + seg*4 + nt (kb<2, seg<7)
constexpr int F_WS = 72;   // kb*12 + nt (kb<6)
constexpr int F_WP = 144;  // kb*4 + nt (kb<4)   Wv rows 0..127
constexpr int F_WQ = 160;  // kb*4 + nt (kb<2)   Wv rows 128..191
constexpr int F_WR = 168;  // kb*4 + nt (kb<2)   Wv rows 192..255
constexpr int NFRAG = 176;

// LDS frag slots: [0,48) W3 segs 0..5 (kb*24+seg*4+nt), [48,120) Ws (kb*12+nt)
// W3 seg 6 stays in global (L2-hot, 8 frags/tile).
constexpr int L_WS = 48;
constexpr int NLDSFRAG = 120;
constexpr int ARENA_OFF = 120 * 1024;  // 8 waves x 4KB (two 2KB slots)
constexpr int SMEM_SZ = 152 * 1024;

constexpr float RS3 = 0.5773502691896258f;  // 1/sqrt(3)
constexpr float RS2 = 0.7071067811865476f;  // 1/sqrt(2)

__device__ __forceinline__ ushort f2b(float f) {
  uint x = __float_as_uint(f);
  return (ushort)((x + 0x7FFFu + ((x >> 16) & 1u)) >> 16);  // RNE
}
__device__ __forceinline__ float fsig(float x) { return 1.0f / (1.0f + __expf(-x)); }
__device__ __forceinline__ float fsilu(float x) { return x / (1.0f + __expf(-x)); }
__device__ __forceinline__ f32x4 MFMA(short8 a, short8 b, f32x4 c) {
  return __builtin_amdgcn_mfma_f32_16x16x32_bf16(
      __builtin_bit_cast(bf16x8, a), __builtin_bit_cast(bf16x8, b), c, 0, 0, 0);
}

// arena tile: 16 rows x 64 bf16 (128 B rows), XOR swizzle on the row stride
__device__ __forceinline__ void cw16(char* ar, int row, int col, ushort v) {
  *(ushort*)(ar + ((row * 128 + col * 2) ^ ((row & 7) << 4))) = v;
}
__device__ __forceinline__ short8 cra(const char* ar, int row, int kb, int lg) {
  return *(const short8*)(ar + ((row * 128 + kb * 64 + lg * 16) ^ ((row & 7) << 4)));
}

// ---------------- B pack: f32 [K][N] -> bf16 frag layout in d_ws ----------------
__global__ void pack_weights(const float* __restrict__ W1, const float* __restrict__ W2,
                             const float* __restrict__ W3, const float* __restrict__ Ws,
                             const float* __restrict__ Wv, ushort* __restrict__ dst) {
  int f = blockIdx.x, lane = threadIdx.x;
  const float* src; int ldw, kbase, NT, local;
  if (f < 8)        { src = W1; ldw = 64;  kbase = 0;   NT = 4;  local = f; }
  else if (f < 16)  { src = W2; ldw = 64;  kbase = 0;   NT = 4;  local = f - 8; }
  else if (f < 72)  { src = W3; ldw = 448; kbase = 0;   NT = 28; local = f - 16; }
  else if (f < 144) { src = Ws; ldw = 192; kbase = 0;   NT = 12; local = f - 72; }
  else if (f < 160) { src = Wv; ldw = 64;  kbase = 0;   NT = 4;  local = f - 144; }
  else if (f < 168) { src = Wv; ldw = 64;  kbase = 128; NT = 4;  local = f - 160; }
  else              { src = Wv; ldw = 64;  kbase = 192; NT = 4;  local = f - 168; }
  int kb = local / NT, nt = local % NT;
  int k0  = kbase + kb * 32 + (lane >> 4) * 8;
  int col = nt * 16 + (lane & 15);
  ushort* o = dst + ((size_t)f * 64 + lane) * 8;
#pragma unroll
  for (int j = 0; j < 8; ++j) o[j] = f2b(src[(size_t)(k0 + j) * ldw + col]);
}

// ---------------- main fused kernel: weight-stationary, lifetime-trimmed -------
__global__ __launch_bounds__(512, 1) void fctp_main(
    const float* __restrict__ node, const float* __restrict__ eattr,
    const float* __restrict__ es, const float* __restrict__ b1,
    const float* __restrict__ b2, const float* __restrict__ offs,
    const float* __restrict__ bs, const float* __restrict__ g_s,
    const float* __restrict__ b_n, const float* __restrict__ g_v,
    const short8* __restrict__ wsv, float* __restrict__ out, int E) {
  __shared__ __align__(16) char smem[SMEM_SZ];
  const int lane = threadIdx.x & 63, wave = threadIdx.x >> 6;
  const int l15 = lane & 15, lg = lane >> 4;

  // ---- one-time: stage W3 segs 0..5 + Ws fragments into LDS (15/wave) ----
#pragma unroll
  for (int i = 0; i < 15; ++i) {
    int fl = wave * 15 + i;
    int fg = (fl < 48) ? (F_W3 + (fl / 24) * 28 + (fl % 24)) : (F_WS + (fl - 48));
    *(short8*)(smem + fl * 1024 + lane * 16) = wsv[fg * 64 + lane];
  }
  __syncthreads();

  char* arA = smem + ARENA_OFF + wave * 4096;
  char* arB = arA + 2048;
  auto ldsB = [&](int f) -> short8 {
    return *(const short8*)(smem + f * 1024 + lane * 16);
  };

  const int ntiles = (E + 15) >> 4;
  for (int tile = (int)blockIdx.x * 8 + wave; tile < ntiles; tile += (int)gridDim.x * 8) {
    const int e0 = tile * 16;
    int geA = e0 + l15; if (geA >= E) geA = E - 1;
    int geR[4];
    float e0v[4], e1v[4][3];
#pragma unroll
    for (int r = 0; r < 4; ++r) {
      int g = e0 + lg * 4 + r; if (g >= E) g = E - 1;
      geR[r] = g;
      float4 ea = *(const float4*)(eattr + (size_t)g * 4);
      e0v[r] = ea.x; e1v[r][0] = ea.y; e1v[r][1] = ea.z; e1v[r][2] = ea.w;
    }

    // vector-block preload (7 uses: dot, 3x q, 3x t-cross)
    float vn[4][4][3];
#pragma unroll
    for (int r = 0; r < 4; ++r) {
      const float* ni = node + (size_t)geR[r] * kNodeW;
#pragma unroll
      for (int nt = 0; nt < 4; ++nt) {
        const float* vp = ni + 128 + 3 * (nt * 16 + l15);
        vn[r][nt][0] = vp[0]; vn[r][nt][1] = vp[1]; vn[r][nt][2] = vp[2];
      }
    }
    // scalar-block preload (dies after the fused s/p pass below)
    float sn[4][8];
#pragma unroll
    for (int r = 0; r < 4; ++r) {
      const float* ni = node + (size_t)geR[r] * kNodeW;
#pragma unroll
      for (int nt = 0; nt < 8; ++nt) sn[r][nt] = ni[nt * 16 + l15];
    }

    // ---- MLP stage 1 ----
    short8 ah[2];
    {
      short8 aes[2];
#pragma unroll
      for (int kb = 0; kb < 2; ++kb) {
        const float* p = es + (size_t)geA * 64 + kb * 32 + lg * 8;
        float4 xa = *(const float4*)p, xb = *(const float4*)(p + 4);
        short8 a;
        a[0] = (short)f2b(xa.x); a[1] = (short)f2b(xa.y); a[2] = (short)f2b(xa.z); a[3] = (short)f2b(xa.w);
        a[4] = (short)f2b(xb.x); a[5] = (short)f2b(xb.y); a[6] = (short)f2b(xb.z); a[7] = (short)f2b(xb.w);
        aes[kb] = a;
      }
      f32x4 acc[4];
#pragma unroll
      for (int nt = 0; nt < 4; ++nt) { float bv = b1[nt * 16 + l15]; acc[nt] = (f32x4){bv, bv, bv, bv}; }
#pragma unroll
      for (int kb = 0; kb < 2; ++kb)
#pragma unroll
        for (int nt = 0; nt < 4; ++nt)
          acc[nt] = MFMA(aes[kb], wsv[(F_W1 + kb * 4 + nt) * 64 + lane], acc[nt]);
#pragma unroll
      for (int nt = 0; nt < 4; ++nt)
#pragma unroll
        for (int r = 0; r < 4; ++r)
          cw16(arA, lg * 4 + r, nt * 16 + l15, f2b(fsilu(acc[nt][r])));
      ah[0] = cra(arA, l15, 0, lg);
      ah[1] = cra(arA, l15, 1, lg);
    }
    // ---- MLP stage 2 ----
    {
      f32x4 acc[4];
#pragma unroll
      for (int nt = 0; nt < 4; ++nt) { float bv = b2[nt * 16 + l15]; acc[nt] = (f32x4){bv, bv, bv, bv}; }
#pragma unroll
      for (int kb = 0; kb < 2; ++kb)
#pragma unroll
        for (int nt = 0; nt < 4; ++nt)
          acc[nt] = MFMA(ah[kb], wsv[(F_W2 + kb * 4 + nt) * 64 + lane], acc[nt]);
#pragma unroll
      for (int nt = 0; nt < 4; ++nt)
#pragma unroll
        for (int r = 0; r < 4; ++r)
          cw16(arA, lg * 4 + r, nt * 16 + l15, f2b(fsilu(acc[nt][r])));
      ah[0] = cra(arA, l15, 0, lg);
      ah[1] = cra(arA, l15, 1, lg);
    }

    // ---- helpers ----
    auto wseg = [&](int seg, f32x4 (&w)[4]) {
#pragma unroll
      for (int nt = 0; nt < 4; ++nt) {
        float bv = offs[seg * 64 + nt * 16 + l15];
        w[nt] = (f32x4){bv, bv, bv, bv};
      }
      if (seg < 6) {
#pragma unroll
        for (int kb = 0; kb < 2; ++kb)
#pragma unroll
          for (int nt = 0; nt < 4; ++nt)
            w[nt] = MFMA(ah[kb], ldsB(kb * 24 + seg * 4 + nt), w[nt]);
      } else {
#pragma unroll
        for (int kb = 0; kb < 2; ++kb)
#pragma unroll
          for (int nt = 0; nt < 4; ++nt)
            w[nt] = MFMA(ah[kb], wsv[(F_W3 + kb * 28 + 24 + nt) * 64 + lane], w[nt]);
      }
    };
    auto gemm12 = [&](const char* a, int kb0, f32x4 (&sac)[12]) {
      short8 a0 = cra(a, l15, 0, lg), a1 = cra(a, l15, 1, lg);
#pragma unroll
      for (int nt = 0; nt < 12; ++nt) sac[nt] = MFMA(a0, ldsB(L_WS + kb0 * 12 + nt), sac[nt]);
#pragma unroll
      for (int nt = 0; nt < 12; ++nt) sac[nt] = MFMA(a1, ldsB(L_WS + (kb0 + 1) * 12 + nt), sac[nt]);
    };
    auto gemm4 = [&](const char* a, int fb0, int fb1, f32x4 (&ac)[4]) {
      short8 a0 = cra(a, l15, 0, lg), a1 = cra(a, l15, 1, lg);
#pragma unroll
      for (int nt = 0; nt < 4; ++nt) ac[nt] = MFMA(a0, wsv[(fb0 + nt) * 64 + lane], ac[nt]);
#pragma unroll
      for (int nt = 0; nt < 4; ++nt) ac[nt] = MFMA(a1, wsv[(fb1 + nt) * 64 + lane], ac[nt]);
    };

    // ---- fused s/p pass: one sn read feeds both products (dual slots) ----
    f32x4 sacc[12];
#pragma unroll
    for (int nt = 0; nt < 12; ++nt) { float bv = bs[nt * 16 + l15]; sacc[nt] = (f32x4){bv, bv, bv, bv}; }
    f32x4 pacc[4];
#pragma unroll
    for (int nt = 0; nt < 4; ++nt) pacc[nt] = (f32x4){0.f, 0.f, 0.f, 0.f};
    {
      f32x4 wa[4], wb[4];
      // half 0: scal cols 0..63
      wseg(0, wa); wseg(2, wb);
#pragma unroll
      for (int nt = 0; nt < 4; ++nt)
#pragma unroll
        for (int r = 0; r < 4; ++r) {
          float s = sn[r][nt];
          cw16(arA, lg * 4 + r, nt * 16 + l15, f2b(e0v[r] * wa[nt][r] * s));
          cw16(arB, lg * 4 + r, nt * 16 + l15, f2b(wb[nt][r] * s));
        }
      gemm12(arA, 0, sacc);
      gemm4(arB, F_WP, F_WP + 4, pacc);
      // half 1: scal cols 64..127
      wseg(1, wa); wseg(3, wb);
#pragma unroll
      for (int nt = 0; nt < 4; ++nt)
#pragma unroll
        for (int r = 0; r < 4; ++r) {
          float s = sn[r][4 + nt];
          cw16(arA, lg * 4 + r, nt * 16 + l15, f2b(e0v[r] * wa[nt][r] * s));
          cw16(arB, lg * 4 + r, nt * 16 + l15, f2b(wb[nt][r] * s));
        }
      gemm12(arA, 2, sacc);
      gemm4(arB, F_WP + 8, F_WP + 12, pacc);
      // dot pass (o0b): scal cols 128..191
      wseg(5, wa);
#pragma unroll
      for (int nt = 0; nt < 4; ++nt)
#pragma unroll
        for (int r = 0; r < 4; ++r) {
          float dot = vn[r][nt][0] * e1v[r][0] + vn[r][nt][1] * e1v[r][1] +
                      vn[r][nt][2] * e1v[r][2];
          cw16(arA, lg * 4 + r, nt * 16 + l15, f2b(wa[nt][r] * dot * RS3));
        }
      gemm12(arA, 4, sacc);
    }

    // ---- layernorm + silu/gate + scalar store (sacc dies here) ----
    float gate[4][4];
#pragma unroll
    for (int r = 0; r < 4; ++r) {
      float sx = 0.f, sxx = 0.f;
#pragma unroll
      for (int nt = 0; nt < 12; ++nt) { float v = sacc[nt][r]; sx += v; sxx += v * v; }
#pragma unroll
      for (int m = 8; m >= 1; m >>= 1) { sx += __shfl_xor(sx, m); sxx += __shfl_xor(sxx, m); }
      float mean = sx * (1.0f / 192.0f);
      float var  = sxx * (1.0f / 192.0f) - mean * mean;
      float rstd = rsqrtf(var + 1e-5f);
      int geu = e0 + lg * 4 + r;
      bool valid = geu < E;
      float* ob = out + (size_t)(valid ? geu : 0) * kOutW;
#pragma unroll
      for (int nt = 0; nt < 12; ++nt) {
        float s_n = g_s[nt * 16 + l15] * (sacc[nt][r] - mean) * rstd + b_n[nt * 16 + l15];
        if (nt < 8) { if (valid) ob[nt * 16 + l15] = fsilu(s_n); }
        else gate[r][nt - 8] = fsig(s_n);
      }
    }

    // ---- v phase: vl init from pacc (pacc dies), then q and t GEMMs ----
    f32x4 vl[3][4];
#pragma unroll
    for (int c = 0; c < 3; ++c)
#pragma unroll
      for (int nt = 0; nt < 4; ++nt)
#pragma unroll
        for (int r = 0; r < 4; ++r)
          vl[c][nt][r] = pacc[nt][r] * e1v[r][c];
    {
      f32x4 wa[4];
      wseg(4, wa);
#pragma unroll
      for (int c = 0; c < 3; ++c) {
        char* a = (c & 1) ? arB : arA;
#pragma unroll
        for (int nt = 0; nt < 4; ++nt)
#pragma unroll
          for (int r = 0; r < 4; ++r)
            cw16(a, lg * 4 + r, nt * 16 + l15, f2b(wa[nt][r] * vn[r][nt][c]));
        f32x4 q[4];
#pragma unroll
        for (int nt = 0; nt < 4; ++nt) q[nt] = (f32x4){0.f, 0.f, 0.f, 0.f};
        gemm4(a, F_WQ, F_WQ + 4, q);
#pragma unroll
        for (int nt = 0; nt < 4; ++nt)
#pragma unroll
          for (int r = 0; r < 4; ++r)
            vl[c][nt][r] += e0v[r] * q[nt][r];
      }
      wseg(6, wa);
#pragma unroll
      for (int c = 0; c < 3; ++c) {
        const int i1 = (c + 1) % 3, i2 = (c + 2) % 3;
        char* a = (c & 1) ? arB : arA;
#pragma unroll
        for (int nt = 0; nt < 4; ++nt)
#pragma unroll
          for (int r = 0; r < 4; ++r) {
            float cr = vn[r][nt][i1] * e1v[r][i2] - vn[r][nt][i2] * e1v[r][i1];
            cw16(a, lg * 4 + r, nt * 16 + l15, f2b(wa[nt][r] * cr * RS2));
          }
        gemm4(a, F_WR, F_WR + 4, vl[c]);
      }
    }

    // ---- RMS norm + gate + vector store ----
#pragma unroll
    for (int r = 0; r < 4; ++r) {
      float vsq = 0.f;
#pragma unroll
      for (int c = 0; c < 3; ++c)
#pragma unroll
        for (int nt = 0; nt < 4; ++nt) { float v = vl[c][nt][r]; vsq += v * v; }
#pragma unroll
      for (int m = 8; m >= 1; m >>= 1) vsq += __shfl_xor(vsq, m);
      float vnrm = rsqrtf(vsq * (1.0f / 64.0f) + 1e-5f);
      int geu = e0 + lg * 4 + r;
      if (geu < E) {
        float* ob = out + (size_t)geu * kOutW + 128;
#pragma unroll
        for (int nt = 0; nt < 4; ++nt) {
          float m3 = g_v[nt * 16 + l15] * vnrm * gate[r][nt];
          int o3 = (nt * 16 + l15) * 3;
          ob[o3 + 0] = m3 * vl[0][nt][r];
          ob[o3 + 1] = m3 * vl[1][nt][r];
          ob[o3 + 2] = m3 * vl[2][nt][r];
        }
      }
    }
  }
}

}  // namespace

extern "C" void kernel_launch(void* const* d_in, const int* in_sizes, int n_in,
                              void* d_out, int out_size, void* d_ws, size_t ws_size,
                              hipStream_t stream) {
  const float* node_input   = (const float*)d_in[0];
  const float* edge_attr    = (const float*)d_in[1];
  const float* edge_scalars = (const float*)d_in[2];
  const float* W1 = (const float*)d_in[3];
  const float* b1 = (const float*)d_in[4];
  const float* W2 = (const float*)d_in[5];
  const float* b2 = (const float*)d_in[6];
  const float* W3 = (const float*)d_in[7];
  const float* offset = (const float*)d_in[8];
  const float* Ws = (const float*)d_in[9];
  const float* bs = (const float*)d_in[10];
  const float* Wv = (const float*)d_in[11];
  const float* g_s = (const float*)d_in[12];
  const float* b_n = (const float*)d_in[13];
  const float* g_v = (const float*)d_in[14];
  float* out = (float*)d_out;

  const int E = in_sizes[0] / kNodeW;

  pack_weights<<<NFRAG, 64, 0, stream>>>(W1, W2, W3, Ws, Wv, (ushort*)d_ws);

  const int ntiles = (E + 15) / 16;
  int blocks = (ntiles + 7) / 8;
  if (blocks > 256) blocks = 256;
  fctp_main<<<blocks, 512, 0, stream>>>(
      node_input, edge_attr, edge_scalars, b1, b2, offset, bs, g_s, b_n, g_v,
      (const short8*)d_ws, out, E);
}

// Round 9
// 306.413 us; speedup vs baseline: 1.2522x; 1.2522x over previous
//
#include <hip/hip_runtime.h>

typedef short short8 __attribute__((ext_vector_type(8)));
typedef __bf16 bf16x8 __attribute__((ext_vector_type(8)));
typedef float f32x4 __attribute__((ext_vector_type(4)));

namespace {

constexpr int kNodeW = 320;   // NS + 3*NV
constexpr int kOutW  = 320;   // NS + 3*VOUT

// wsv frag indices (packed by pack_weights); 1 frag = 64 lanes * 16 B = 1 KB
constexpr int F_W1 = 0;    // kb*4 + nt (kb<2)
constexpr int F_W2 = 8;
constexpr int F_W3 = 16;   // kb*28 + seg*4 + nt (kb<2, seg<7)
constexpr int F_WS = 72;   // kb*12 + nt (kb<6)
constexpr int F_WP = 144;  // kb*4 + nt (kb<4)   Wv rows 0..127
constexpr int F_WQ = 160;  // kb*4 + nt (kb<2)   Wv rows 128..191
constexpr int F_WR = 168;  // kb*4 + nt (kb<2)   Wv rows 192..255
constexpr int NFRAG = 176;

// per-tile ws intermediate layout (chunk-local tile ct, lane):
//   pacc f32 : ct*4096 + lane*64 + (nt*4+r)*4      (4 KB/tile)
//   w4  bf16 : ct*2048 + lane*32 + (nt*4+r)*2      (2 KB/tile)
//   w5  bf16 : same stride                          (2 KB/tile)
//   gate bf16: same stride                          (2 KB/tile)
constexpr int TILE_WS_BYTES = 10240;
constexpr size_t WS_INTER_BASE = 262144;  // frags live in [0, 176KB)

constexpr float RS3 = 0.5773502691896258f;  // 1/sqrt(3)
constexpr float RS2 = 0.7071067811865476f;  // 1/sqrt(2)

__device__ __forceinline__ ushort f2b(float f) {
  uint x = __float_as_uint(f);
  return (ushort)((x + 0x7FFFu + ((x >> 16) & 1u)) >> 16);  // RNE
}
__device__ __forceinline__ float b2f(ushort u) {
  return __uint_as_float(((uint)u) << 16);
}
__device__ __forceinline__ float fsig(float x) { return 1.0f / (1.0f + __expf(-x)); }
__device__ __forceinline__ float fsilu(float x) { return x / (1.0f + __expf(-x)); }
__device__ __forceinline__ f32x4 MFMA(short8 a, short8 b, f32x4 c) {
  return __builtin_amdgcn_mfma_f32_16x16x32_bf16(
      __builtin_bit_cast(bf16x8, a), __builtin_bit_cast(bf16x8, b), c, 0, 0, 0);
}

// arena tile: 16 rows x 64 bf16 (128 B rows), XOR swizzle on the row stride
__device__ __forceinline__ void cw16(char* ar, int row, int col, ushort v) {
  *(ushort*)(ar + ((row * 128 + col * 2) ^ ((row & 7) << 4))) = v;
}
__device__ __forceinline__ short8 cra(const char* ar, int row, int kb, int lg) {
  return *(const short8*)(ar + ((row * 128 + kb * 64 + lg * 16) ^ ((row & 7) << 4)));
}

// ---------------- B pack: f32 [K][N] -> bf16 frag layout in d_ws ----------------
__global__ void pack_weights(const float* __restrict__ W1, const float* __restrict__ W2,
                             const float* __restrict__ W3, const float* __restrict__ Ws,
                             const float* __restrict__ Wv, ushort* __restrict__ dst) {
  int f = blockIdx.x, lane = threadIdx.x;
  const float* src; int ldw, kbase, NT, local;
  if (f < 8)        { src = W1; ldw = 64;  kbase = 0;   NT = 4;  local = f; }
  else if (f < 16)  { src = W2; ldw = 64;  kbase = 0;   NT = 4;  local = f - 8; }
  else if (f < 72)  { src = W3; ldw = 448; kbase = 0;   NT = 28; local = f - 16; }
  else if (f < 144) { src = Ws; ldw = 192; kbase = 0;   NT = 12; local = f - 72; }
  else if (f < 160) { src = Wv; ldw = 64;  kbase = 0;   NT = 4;  local = f - 144; }
  else if (f < 168) { src = Wv; ldw = 64;  kbase = 128; NT = 4;  local = f - 160; }
  else              { src = Wv; ldw = 64;  kbase = 192; NT = 4;  local = f - 168; }
  int kb = local / NT, nt = local % NT;
  int k0  = kbase + kb * 32 + (lane >> 4) * 8;
  int col = nt * 16 + (lane & 15);
  ushort* o = dst + ((size_t)f * 64 + lane) * 8;
#pragma unroll
  for (int j = 0; j < 8; ++j) o[j] = f2b(src[(size_t)(k0 + j) * ldw + col]);
}

// ================= Kernel A: MLP + scalar path; emits pacc/w4/w5/gate ==========
__global__ __launch_bounds__(512, 1) void fctp_scal(
    const float* __restrict__ node, const float* __restrict__ eattr,
    const float* __restrict__ es, const float* __restrict__ b1,
    const float* __restrict__ b2, const float* __restrict__ offs,
    const float* __restrict__ bs, const float* __restrict__ g_s,
    const float* __restrict__ b_n, const short8* __restrict__ wsv,
    float* __restrict__ out,
    float* __restrict__ ws_pacc, ushort* __restrict__ ws_w4,
    ushort* __restrict__ ws_w5, ushort* __restrict__ ws_gate,
    int t0, int tc, int E) {
  __shared__ __align__(16) char smem[144 * 1024];
  const int lane = threadIdx.x & 63, wave = threadIdx.x >> 6;
  const int l15 = lane & 15, lg = lane >> 4;

  // stage W3 (slots 0..55, kb*28+seg*4+nt) + Ws (slots 56..127, 56+kb*12+nt)
#pragma unroll
  for (int i = 0; i < 16; ++i) {
    int fl = wave * 16 + i;
    int fg = (fl < 56) ? (F_W3 + fl) : (F_WS + (fl - 56));
    *(short8*)(smem + fl * 1024 + lane * 16) = wsv[fg * 64 + lane];
  }
  __syncthreads();

  char* ar = smem + 128 * 1024 + wave * 2048;
  auto ldsB = [&](int f) -> short8 {
    return *(const short8*)(smem + f * 1024 + lane * 16);
  };

  for (int ct = (int)blockIdx.x * 8 + wave; ct < tc; ct += (int)gridDim.x * 8) {
    const int e0 = (t0 + ct) * 16;
    int geA = e0 + l15; if (geA >= E) geA = E - 1;
    int geR[4];
    float e0v[4], e1v[4][3];
#pragma unroll
    for (int r = 0; r < 4; ++r) {
      int g = e0 + lg * 4 + r; if (g >= E) g = E - 1;
      geR[r] = g;
      float4 ea = *(const float4*)(eattr + (size_t)g * 4);
      e0v[r] = ea.x; e1v[r][0] = ea.y; e1v[r][1] = ea.z; e1v[r][2] = ea.w;
    }
    float sn[4][8];
#pragma unroll
    for (int r = 0; r < 4; ++r) {
      const float* ni = node + (size_t)geR[r] * kNodeW;
#pragma unroll
      for (int nt = 0; nt < 8; ++nt) sn[r][nt] = ni[nt * 16 + l15];
    }

    // ---- MLP stage 1 ----
    short8 ah[2];
    {
      short8 aes[2];
#pragma unroll
      for (int kb = 0; kb < 2; ++kb) {
        const float* p = es + (size_t)geA * 64 + kb * 32 + lg * 8;
        float4 xa = *(const float4*)p, xb = *(const float4*)(p + 4);
        short8 a;
        a[0] = (short)f2b(xa.x); a[1] = (short)f2b(xa.y); a[2] = (short)f2b(xa.z); a[3] = (short)f2b(xa.w);
        a[4] = (short)f2b(xb.x); a[5] = (short)f2b(xb.y); a[6] = (short)f2b(xb.z); a[7] = (short)f2b(xb.w);
        aes[kb] = a;
      }
      f32x4 acc[4];
#pragma unroll
      for (int nt = 0; nt < 4; ++nt) { float bv = b1[nt * 16 + l15]; acc[nt] = (f32x4){bv, bv, bv, bv}; }
#pragma unroll
      for (int kb = 0; kb < 2; ++kb)
#pragma unroll
        for (int nt = 0; nt < 4; ++nt)
          acc[nt] = MFMA(aes[kb], wsv[(F_W1 + kb * 4 + nt) * 64 + lane], acc[nt]);
#pragma unroll
      for (int nt = 0; nt < 4; ++nt)
#pragma unroll
        for (int r = 0; r < 4; ++r)
          cw16(ar, lg * 4 + r, nt * 16 + l15, f2b(fsilu(acc[nt][r])));
      ah[0] = cra(ar, l15, 0, lg);
      ah[1] = cra(ar, l15, 1, lg);
    }
    // ---- MLP stage 2 ----
    {
      f32x4 acc[4];
#pragma unroll
      for (int nt = 0; nt < 4; ++nt) { float bv = b2[nt * 16 + l15]; acc[nt] = (f32x4){bv, bv, bv, bv}; }
#pragma unroll
      for (int kb = 0; kb < 2; ++kb)
#pragma unroll
        for (int nt = 0; nt < 4; ++nt)
          acc[nt] = MFMA(ah[kb], wsv[(F_W2 + kb * 4 + nt) * 64 + lane], acc[nt]);
#pragma unroll
      for (int nt = 0; nt < 4; ++nt)
#pragma unroll
        for (int r = 0; r < 4; ++r)
          cw16(ar, lg * 4 + r, nt * 16 + l15, f2b(fsilu(acc[nt][r])));
      ah[0] = cra(ar, l15, 0, lg);
      ah[1] = cra(ar, l15, 1, lg);
    }

    auto wseg = [&](int seg, f32x4 (&w)[4]) {
#pragma unroll
      for (int nt = 0; nt < 4; ++nt) {
        float bv = offs[seg * 64 + nt * 16 + l15];
        w[nt] = (f32x4){bv, bv, bv, bv};
      }
#pragma unroll
      for (int kb = 0; kb < 2; ++kb)
#pragma unroll
        for (int nt = 0; nt < 4; ++nt)
          w[nt] = MFMA(ah[kb], ldsB(kb * 28 + seg * 4 + nt), w[nt]);
    };
    auto gemm12 = [&](int kb0, f32x4 (&sac)[12]) {
      short8 a0 = cra(ar, l15, 0, lg), a1 = cra(ar, l15, 1, lg);
#pragma unroll
      for (int nt = 0; nt < 12; ++nt) sac[nt] = MFMA(a0, ldsB(56 + kb0 * 12 + nt), sac[nt]);
#pragma unroll
      for (int nt = 0; nt < 12; ++nt) sac[nt] = MFMA(a1, ldsB(56 + (kb0 + 1) * 12 + nt), sac[nt]);
    };
    auto gemm4g = [&](int fb0, int fb1, f32x4 (&ac)[4]) {  // B-frags from global (L2)
      short8 a0 = cra(ar, l15, 0, lg), a1 = cra(ar, l15, 1, lg);
#pragma unroll
      for (int nt = 0; nt < 4; ++nt) ac[nt] = MFMA(a0, wsv[(fb0 + nt) * 64 + lane], ac[nt]);
#pragma unroll
      for (int nt = 0; nt < 4; ++nt) ac[nt] = MFMA(a1, wsv[(fb1 + nt) * 64 + lane], ac[nt]);
    };
    auto tpS = [&](const f32x4 (&w)[4], int nb, bool mulE0) {
#pragma unroll
      for (int nt = 0; nt < 4; ++nt)
#pragma unroll
        for (int r = 0; r < 4; ++r) {
          float v = w[nt][r] * sn[r][nb + nt];
          if (mulE0) v *= e0v[r];
          cw16(ar, lg * 4 + r, nt * 16 + l15, f2b(v));
        }
    };

    // ---- s + p phases (sequential, one arena slot, one wseg live at a time) ----
    f32x4 sacc[12];
#pragma unroll
    for (int nt = 0; nt < 12; ++nt) { float bv = bs[nt * 16 + l15]; sacc[nt] = (f32x4){bv, bv, bv, bv}; }
    f32x4 pacc[4];
#pragma unroll
    for (int nt = 0; nt < 4; ++nt) pacc[nt] = (f32x4){0.f, 0.f, 0.f, 0.f};
    {
      f32x4 wa[4];
      wseg(0, wa); tpS(wa, 0, true);  gemm12(0, sacc);
      wseg(2, wa); tpS(wa, 0, false); gemm4g(F_WP,     F_WP + 4,  pacc);
      wseg(1, wa); tpS(wa, 4, true);  gemm12(2, sacc);
      wseg(3, wa); tpS(wa, 4, false); gemm4g(F_WP + 8, F_WP + 12, pacc);
      // dot pass (o0b): vector block read on the fly (single use)
      wseg(5, wa);
#pragma unroll
      for (int nt = 0; nt < 4; ++nt)
#pragma unroll
        for (int r = 0; r < 4; ++r) {
          const float* vp = node + (size_t)geR[r] * kNodeW + 128 + 3 * (nt * 16 + l15);
          float dot = vp[0] * e1v[r][0] + vp[1] * e1v[r][1] + vp[2] * e1v[r][2];
          cw16(ar, lg * 4 + r, nt * 16 + l15, f2b(wa[nt][r] * dot * RS3));
        }
      gemm12(4, sacc);
    }

    // ---- store pacc (f32) ----
    {
      float* pd = ws_pacc + (size_t)ct * 1024 + lane * 16;
#pragma unroll
      for (int nt = 0; nt < 4; ++nt)
        *(f32x4*)(pd + nt * 4) = pacc[nt];
    }

    // ---- layernorm + silu + scalar store; gate -> ws (bf16) ----
#pragma unroll
    for (int r = 0; r < 4; ++r) {
      float sx = 0.f, sxx = 0.f;
#pragma unroll
      for (int nt = 0; nt < 12; ++nt) { float v = sacc[nt][r]; sx += v; sxx += v * v; }
#pragma unroll
      for (int m = 8; m >= 1; m >>= 1) { sx += __shfl_xor(sx, m); sxx += __shfl_xor(sxx, m); }
      float mean = sx * (1.0f / 192.0f);
      float var  = sxx * (1.0f / 192.0f) - mean * mean;
      float rstd = rsqrtf(var + 1e-5f);
      int geu = e0 + lg * 4 + r;
      bool valid = geu < E;
      float* ob = out + (size_t)(valid ? geu : 0) * kOutW;
      ushort* gd = ws_gate + (size_t)ct * 1024 + lane * 16;
#pragma unroll
      for (int nt = 0; nt < 12; ++nt) {
        float s_n = g_s[nt * 16 + l15] * (sacc[nt][r] - mean) * rstd + b_n[nt * 16 + l15];
        if (nt < 8) { if (valid) ob[nt * 16 + l15] = fsilu(s_n); }
        else gd[(nt - 8) * 4 + r] = f2b(fsig(s_n));
      }
    }

    // ---- w4 / w5 coefficient stores (bf16) ----
    {
      f32x4 wa[4];
      wseg(4, wa);
      ushort* wd = ws_w4 + (size_t)ct * 1024 + lane * 16;
#pragma unroll
      for (int nt = 0; nt < 4; ++nt)
#pragma unroll
        for (int r = 0; r < 4; ++r) wd[nt * 4 + r] = f2b(wa[nt][r]);
      wseg(6, wa);
      wd = ws_w5 + (size_t)ct * 1024 + lane * 16;
#pragma unroll
      for (int nt = 0; nt < 4; ++nt)
#pragma unroll
        for (int r = 0; r < 4; ++r) wd[nt * 4 + r] = f2b(wa[nt][r]);
    }
  }
}

// ================= Kernel B: vector path (q, t-cross, RMS, gate) ===============
__global__ __launch_bounds__(256, 2) void fctp_vec(
    const float* __restrict__ node, const float* __restrict__ eattr,
    const short8* __restrict__ wsv, float* __restrict__ out,
    const float* __restrict__ ws_pacc, const ushort* __restrict__ ws_w4,
    const ushort* __restrict__ ws_w5, const ushort* __restrict__ ws_gate,
    const float* __restrict__ g_v, int t0, int tc, int E) {
  __shared__ __align__(16) char smem[24 * 1024];
  const int lane = threadIdx.x & 63, wave = threadIdx.x >> 6;
  const int l15 = lane & 15, lg = lane >> 4;

  // stage WQ (slots 0..7 = kb*4+nt) + WR (slots 8..15)
#pragma unroll
  for (int i = 0; i < 4; ++i) {
    int fl = wave * 4 + i;
    int fg = (fl < 8) ? (F_WQ + fl) : (F_WR + (fl - 8));
    *(short8*)(smem + fl * 1024 + lane * 16) = wsv[fg * 64 + lane];
  }
  __syncthreads();

  char* ar = smem + 16 * 1024 + wave * 2048;
  auto ldsB = [&](int f) -> short8 {
    return *(const short8*)(smem + f * 1024 + lane * 16);
  };

  for (int ct = (int)blockIdx.x * 4 + wave; ct < tc; ct += (int)gridDim.x * 4) {
    const int e0 = (t0 + ct) * 16;
    int geR[4];
    float e0v[4], e1v[4][3];
#pragma unroll
    for (int r = 0; r < 4; ++r) {
      int g = e0 + lg * 4 + r; if (g >= E) g = E - 1;
      geR[r] = g;
      float4 ea = *(const float4*)(eattr + (size_t)g * 4);
      e0v[r] = ea.x; e1v[r][0] = ea.y; e1v[r][1] = ea.z; e1v[r][2] = ea.w;
    }
    float vn[4][4][3];
#pragma unroll
    for (int r = 0; r < 4; ++r) {
      const float* ni = node + (size_t)geR[r] * kNodeW + 128;
#pragma unroll
      for (int nt = 0; nt < 4; ++nt) {
        const float* vp = ni + 3 * (nt * 16 + l15);
        vn[r][nt][0] = vp[0]; vn[r][nt][1] = vp[1]; vn[r][nt][2] = vp[2];
      }
    }
    float w4f[16], w5f[16];
    {
      const ushort* p4 = ws_w4 + (size_t)ct * 1024 + lane * 16;
      const ushort* p5 = ws_w5 + (size_t)ct * 1024 + lane * 16;
      short8 a4 = *(const short8*)p4, b4 = *(const short8*)(p4 + 8);
      short8 a5 = *(const short8*)p5, b5 = *(const short8*)(p5 + 8);
#pragma unroll
      for (int j = 0; j < 8; ++j) {
        w4f[j] = b2f((ushort)a4[j]); w4f[8 + j] = b2f((ushort)b4[j]);
        w5f[j] = b2f((ushort)a5[j]); w5f[8 + j] = b2f((ushort)b5[j]);
      }
    }

    // vl init from pacc (transient loads)
    f32x4 vl[3][4];
    {
      const float* pd = ws_pacc + (size_t)ct * 1024 + lane * 16;
#pragma unroll
      for (int nt = 0; nt < 4; ++nt) {
        f32x4 p = *(const f32x4*)(pd + nt * 4);
#pragma unroll
        for (int c = 0; c < 3; ++c)
#pragma unroll
          for (int r = 0; r < 4; ++r)
            vl[c][nt][r] = p[r] * e1v[r][c];
      }
    }

    auto gemmL = [&](int sb, f32x4 (&ac)[4]) {  // B-frags from block LDS
      short8 a0 = cra(ar, l15, 0, lg), a1 = cra(ar, l15, 1, lg);
#pragma unroll
      for (int nt = 0; nt < 4; ++nt) ac[nt] = MFMA(a0, ldsB(sb + nt), ac[nt]);
#pragma unroll
      for (int nt = 0; nt < 4; ++nt) ac[nt] = MFMA(a1, ldsB(sb + 4 + nt), ac[nt]);
    };

    // q phase: e0 folded into TP product -> accumulate straight into vl[c]
#pragma unroll
    for (int c = 0; c < 3; ++c) {
#pragma unroll
      for (int nt = 0; nt < 4; ++nt)
#pragma unroll
        for (int r = 0; r < 4; ++r)
          cw16(ar, lg * 4 + r, nt * 16 + l15,
               f2b(e0v[r] * w4f[nt * 4 + r] * vn[r][nt][c]));
      gemmL(0, vl[c]);
    }
    // t phase: cross product in the TP, accumulate into vl[c]
#pragma unroll
    for (int c = 0; c < 3; ++c) {
      const int i1 = (c + 1) % 3, i2 = (c + 2) % 3;
#pragma unroll
      for (int nt = 0; nt < 4; ++nt)
#pragma unroll
        for (int r = 0; r < 4; ++r) {
          float cr = vn[r][nt][i1] * e1v[r][i2] - vn[r][nt][i2] * e1v[r][i1];
          cw16(ar, lg * 4 + r, nt * 16 + l15, f2b(w5f[nt * 4 + r] * cr * RS2));
        }
      gemmL(8, vl[c]);
    }

    // RMS + gate + store
    const ushort* gd = ws_gate + (size_t)ct * 1024 + lane * 16;
#pragma unroll
    for (int r = 0; r < 4; ++r) {
      float vsq = 0.f;
#pragma unroll
      for (int c = 0; c < 3; ++c)
#pragma unroll
        for (int nt = 0; nt < 4; ++nt) { float v = vl[c][nt][r]; vsq += v * v; }
#pragma unroll
      for (int m = 8; m >= 1; m >>= 1) vsq += __shfl_xor(vsq, m);
      float vnrm = rsqrtf(vsq * (1.0f / 64.0f) + 1e-5f);
      int geu = e0 + lg * 4 + r;
      if (geu < E) {
        float* ob = out + (size_t)geu * kOutW + 128;
#pragma unroll
        for (int nt = 0; nt < 4; ++nt) {
          float m3 = g_v[nt * 16 + l15] * vnrm * b2f(gd[nt * 4 + r]);
          int o3 = (nt * 16 + l15) * 3;
          ob[o3 + 0] = m3 * vl[0][nt][r];
          ob[o3 + 1] = m3 * vl[1][nt][r];
          ob[o3 + 2] = m3 * vl[2][nt][r];
        }
      }
    }
  }
}

}  // namespace

extern "C" void kernel_launch(void* const* d_in, const int* in_sizes, int n_in,
                              void* d_out, int out_size, void* d_ws, size_t ws_size,
                              hipStream_t stream) {
  const float* node_input   = (const float*)d_in[0];
  const float* edge_attr    = (const float*)d_in[1];
  const float* edge_scalars = (const float*)d_in[2];
  const float* W1 = (const float*)d_in[3];
  const float* b1 = (const float*)d_in[4];
  const float* W2 = (const float*)d_in[5];
  const float* b2 = (const float*)d_in[6];
  const float* W3 = (const float*)d_in[7];
  const float* offset = (const float*)d_in[8];
  const float* Ws = (const float*)d_in[9];
  const float* bs = (const float*)d_in[10];
  const float* Wv = (const float*)d_in[11];
  const float* g_s = (const float*)d_in[12];
  const float* b_n = (const float*)d_in[13];
  const float* g_v = (const float*)d_in[14];
  float* out = (float*)d_out;

  const int E = in_sizes[0] / kNodeW;
  const int ntiles = (E + 15) / 16;

  pack_weights<<<NFRAG, 64, 0, stream>>>(W1, W2, W3, Ws, Wv, (ushort*)d_ws);

  // chunk sizing from ws_size (deterministic: ws_size is fixed per session)
  size_t avail = (ws_size > WS_INTER_BASE) ? ws_size - WS_INTER_BASE : 0;
  int tpc = (int)((avail / TILE_WS_BYTES < (size_t)ntiles) ? avail / TILE_WS_BYTES
                                                           : (size_t)ntiles);
  if (tpc < 1) tpc = 1;

  char* base = (char*)d_ws + WS_INTER_BASE;
  float*  ws_pacc = (float*)base;
  ushort* ws_w4   = (ushort*)(base + (size_t)tpc * 4096);
  ushort* ws_w5   = (ushort*)(base + (size_t)tpc * 4096 + (size_t)tpc * 2048);
  ushort* ws_gate = (ushort*)(base + (size_t)tpc * 4096 + (size_t)tpc * 4096);

  for (int t0 = 0; t0 < ntiles; t0 += tpc) {
    int tc = ntiles - t0 < tpc ? ntiles - t0 : tpc;
    int blkA = (tc + 7) / 8; if (blkA > 256) blkA = 256;
    fctp_scal<<<blkA, 512, 0, stream>>>(
        node_input, edge_attr, edge_scalars, b1, b2, offset, bs, g_s, b_n,
        (const short8*)d_ws, out, ws_pacc, ws_w4, ws_w5, ws_gate, t0, tc, E);
    int blkB = (tc + 3) / 4; if (blkB > 512) blkB = 512;
    fctp_vec<<<blkB, 256, 0, stream>>>(
        node_input, edge_attr, (const short8*)d_ws, out, ws_pacc, ws_w4, ws_w5,
        ws_gate, g_v, t0, tc, E);
  }
}